// Round 5
// baseline (2933.344 us; speedup 1.0000x reference)
//
#include <hip/hip_runtime.h>
#include <hip/hip_bf16.h>

#define B_ 64
#define S_ 512
#define D_ 256
#define H_ 512

typedef __attribute__((ext_vector_type(8))) short bf16x8;
typedef __attribute__((ext_vector_type(4))) float f32x4;
typedef __attribute__((ext_vector_type(4))) unsigned int uint4v;
typedef unsigned short ushort_t;

__device__ __forceinline__ ushort_t f2bf(float f) {
    __hip_bfloat16 h = __float2bfloat16(f);   // RNE rounding
    return *reinterpret_cast<ushort_t*>(&h);
}
__device__ __forceinline__ float sigmoid_f(float x) { return 1.f / (1.f + __expf(-x)); }
__device__ __forceinline__ float tanh_f(float x) { return 1.f - 2.f / (__expf(2.f * x) + 1.f); }

__device__ __forceinline__ void lds_barrier() {
    asm volatile("s_waitcnt lgkmcnt(0)\n\ts_barrier" ::: "memory");
}

// R14: L2-RMW signal plane (both sides RMW -> coherence by construction),
// wave0-only polling, accA hoist, ws-safe (352KB, vs R13's risky 1.26MB).
//  * Release (uniform) = global_atomic_swap (no-return) on word A: executes
//    at the XCD-local L2. Poll = inline-asm global_atomic_add(+0) sc0 on the
//    same word: same L2 serialization point -> guaranteed to observe the
//    swap. No reliance on sc1-store-updates-L2 semantics (R13's hole); no
//    InstCombine idempotent-RMW->load hazard (asm).
//  * Termination guarantee: release also posts word B (separate 64B-aligned
//    offset) via sc0 sc1 write-through store (R7-proven pairing with agent
//    atomic loads). Poll is bounded (16 rounds) then falls back to the
//    R0-proven agent/L3 loop on word B. Sticky-disable of the fast path if
//    it provably missed a posted flag. A hang is structurally impossible.
//  * Only wave 0 polls (64 lanes x 64 flags, 1 RMW/lane/round); waves 1-7
//    wait at barrier P. 8x less flag traffic than R0's all-wave storm.
//  * accA (x-GEMM, 16 MFMAs, h-independent) hoisted between poll issue and
//    resolve: hides the RMW round trip.
//  * Data plane: R0-proven verbatim (uniform: sc0/sc0 same-XCD L2; mixed:
//    sc0 sc1 both sides). 3-slot hbuf rotation. pred head: R0's atomicAdd.
__global__ __launch_bounds__(512) void lstm_rec(
    const float* __restrict__ X,
    const float* __restrict__ Wf, const float* __restrict__ Wi,
    const float* __restrict__ Wo, const float* __restrict__ Wc,
    const float* __restrict__ bfp, const float* __restrict__ bip,
    const float* __restrict__ bop, const float* __restrict__ bcp,
    const float* __restrict__ Uf, const float* __restrict__ Ui,
    const float* __restrict__ Uo, const float* __restrict__ Uc,
    const float* __restrict__ Wfc,
    float* __restrict__ pred, unsigned int* __restrict__ hbufU,
    unsigned int* __restrict__ flags, unsigned int* __restrict__ xcdtab,
    float* __restrict__ outH, float* __restrict__ outC)
{
    __shared__ ushort_t hS[16 * 520];
    __shared__ ushort_t xS[16 * 264];
    __shared__ float gact[4][16][68];
    __shared__ int meta[2];   // [0]=rank, [1]=uniform

    const int tid  = threadIdx.x;
    const int w    = tid >> 6;
    const int lane = tid & 63;
    const int q    = lane >> 4;
    const int m    = lane & 15;
    const int gate = w >> 1;
    const int half = w & 1;

    // ---- XCD self-assignment: wave 0 computes, LDS-broadcasts (R9-proven) ----
    if (w == 0) {
        unsigned int xcd;
        asm volatile("s_getreg_b32 %0, hwreg(HW_REG_XCC_ID)" : "=s"(xcd));
        xcd &= 15u;
        if (lane == 0)
            __hip_atomic_store(&xcdtab[blockIdx.x], xcd + 1u,
                               __ATOMIC_RELEASE, __HIP_MEMORY_SCOPE_AGENT);
        unsigned int entry;
        for (;;) {
            entry = __hip_atomic_load(&xcdtab[lane], __ATOMIC_ACQUIRE, __HIP_MEMORY_SCOPE_AGENT);
            if (__ballot(entry != 0u) == ~0ull) break;
            __builtin_amdgcn_s_sleep(1);
        }
        const unsigned int xcd_j = entry - 1u;
        const unsigned int key_j = (xcd_j << 8) | (unsigned int)lane;
        const unsigned int mykey = (xcd << 8) | (unsigned int)blockIdx.x;
        const int rank = __popcll(__ballot(key_j < mykey));
        const int c_lt = __popcll(__ballot(xcd_j < xcd));
        const int c_eq = __popcll(__ballot(xcd_j == xcd));
        const int gg   = rank >> 3;
        const bool uni = (c_lt <= gg * 8) && (gg * 8 + 8 <= c_lt + c_eq);
        if (lane == 0) { meta[0] = rank; meta[1] = uni ? 1 : 0; }
    }
    __syncthreads();
    const int  rank    = meta[0];
    const bool uniform = meta[1] != 0;
    if (rank >= 32) return;
    const int g = rank >> 3;
    const int s = rank & 7;

    const int ncol0 = s * 64 + half * 32 + m;
    const int ncol1 = ncol0 + 16;

    const float* Ug = (gate == 0) ? Uf : (gate == 1) ? Ui : (gate == 2) ? Uo : Uc;
    const float* Wg = (gate == 0) ? Wf : (gate == 1) ? Wi : (gate == 2) ? Wo : Wc;
    const float* bg = (gate == 0) ? bfp : (gate == 1) ? bip : (gate == 2) ? bop : bcp;

    const float bias0 = bg[ncol0];
    const float bias1 = bg[ncol1];

    // ---- one-time: B-fragments into registers (fp32 -> bf16 RNE) ----
    bf16x8 UF[2][16];
    bf16x8 WF[2][8];
    #pragma unroll
    for (int tt = 0; tt < 2; ++tt) {
        const int nc = tt ? ncol1 : ncol0;
        #pragma unroll
        for (int ks = 0; ks < 16; ++ks) {
            bf16x8 v;
            #pragma unroll
            for (int j = 0; j < 8; ++j)
                v[j] = (short)f2bf(Ug[(ks * 32 + q * 8 + j) * H_ + nc]);
            UF[tt][ks] = v;
        }
        #pragma unroll
        for (int ks = 0; ks < 8; ++ks) {
            bf16x8 v;
            #pragma unroll
            for (int j = 0; j < 8; ++j)
                v[j] = (short)f2bf(Wg[(ks * 32 + q * 8 + j) * H_ + nc]);
            WF[tt][ks] = v;
        }
    }

    const int urow  = tid >> 5;
    const int upair = tid & 31;
    const float2 wfc2 = *(const float2*)&Wfc[s * 64 + 2 * upair];

    float cr0 = 0.f, cr1 = 0.f;

    // flags: 64 per group, stride 32 u32 (128B). word A = +0 (RMW plane),
    // word B = +16 (store-through plane, own 64B half).
    unsigned int* flagsG = flags + g * 64 * 32;
    const int myflag = s * 8 + w;
    bool rmw_ok = true;   // wave0 state: fast RMW path enabled

    // ---- preamble: stage x(0) into LDS ----
    {
        const float* xsrc = &X[((size_t)(g * 16 + urow) * S_ + 0) * D_ + upair * 8];
        float4 a = *(const float4*)xsrc;
        float4 b = *(const float4*)(xsrc + 4);
        bf16x8 v;
        v[0] = (short)f2bf(a.x); v[1] = (short)f2bf(a.y);
        v[2] = (short)f2bf(a.z); v[3] = (short)f2bf(a.w);
        v[4] = (short)f2bf(b.x); v[5] = (short)f2bf(b.y);
        v[6] = (short)f2bf(b.z); v[7] = (short)f2bf(b.w);
        *(bf16x8*)&xS[urow * 264 + upair * 8] = v;
    }

    float4 xr0, xr1;

    for (int t = 0; t < S_; ++t) {
        lds_barrier();   // T: xS(t) visible (G(t-1)/preamble); gact reads done

        const unsigned int tgt = (unsigned int)t;
        const bool doPoll = (t > 0);
        unsigned int fv1 = 0;

        // ---- C1: wave0 issues RMW poll round-1 (no wait) ----
        if (doPoll && w == 0 && uniform && rmw_ok) {
            asm volatile("global_atomic_add %0, %1, %2, off sc0"
                         : "=v"(fv1) : "v"(&flagsG[lane * 32]), "v"(0u) : "memory");
        }

        // ---- C2: accA = x-GEMM on xS(t) (h-independent; hides the RMW RT) ----
        f32x4 accA0 = {bias0, bias0, bias0, bias0};
        f32x4 accA1 = {bias1, bias1, bias1, bias1};
        #pragma unroll
        for (int ks = 0; ks < 8; ++ks) {
            bf16x8 a = *(const bf16x8*)&xS[m * 264 + ks * 32 + q * 8];
            accA0 = __builtin_amdgcn_mfma_f32_16x16x32_bf16(a, WF[0][ks], accA0, 0, 0, 0);
            accA1 = __builtin_amdgcn_mfma_f32_16x16x32_bf16(a, WF[1][ks], accA1, 0, 0, 0);
        }

        // ---- C3: wave0 resolves the poll; waves 1-7 go wait at P ----
        if (doPoll && w == 0) {
            if (uniform && rmw_ok) {
                asm volatile("s_waitcnt vmcnt(0)" : "+v"(fv1) :: "memory");
                __builtin_amdgcn_sched_barrier(0);
                bool done = (__ballot(fv1 >= tgt) == ~0ull);
                int rounds = 0;
                while (!done && rounds < 16) {
                    ++rounds;
                    if (rounds > 2) __builtin_amdgcn_s_sleep(1);
                    asm volatile("global_atomic_add %0, %1, %2, off sc0\n\t"
                                 "s_waitcnt vmcnt(0)"
                                 : "=v"(fv1) : "v"(&flagsG[lane * 32]), "v"(0u) : "memory");
                    __builtin_amdgcn_sched_barrier(0);
                    done = (__ballot(fv1 >= tgt) == ~0ull);
                }
                if (!done) {
                    // fallback: word B via agent/L3 (guaranteed terminating)
                    unsigned int fb = __hip_atomic_load(&flagsG[lane * 32 + 16],
                                                        __ATOMIC_RELAXED, __HIP_MEMORY_SCOPE_AGENT);
                    if (__ballot(fb >= tgt) == ~0ull) {
                        rmw_ok = false;   // A-plane provably missed a posted flag
                    } else {
                        for (;;) {
                            __builtin_amdgcn_s_sleep(1);
                            fb = __hip_atomic_load(&flagsG[lane * 32 + 16],
                                                   __ATOMIC_RELAXED, __HIP_MEMORY_SCOPE_AGENT);
                            if (__ballot(fb >= tgt) == ~0ull) break;
                        }
                    }
                }
            } else {
                for (;;) {
                    unsigned int fb = __hip_atomic_load(&flagsG[lane * 32 + 16],
                                                        __ATOMIC_RELAXED, __HIP_MEMORY_SCOPE_AGENT);
                    if (__ballot(fb >= tgt) == ~0ull) break;
                    __builtin_amdgcn_s_sleep(1);
                }
            }
        }
        lds_barrier();   // P: poll resolved -> whole block may read h(t)

        // ---- C4: stage h(t) [16x512] into LDS (R0-proven data plane) ----
        {
            const int row  = tid >> 5;
            const int dcol = (tid & 31) * 8;
            const unsigned int* p0 = &hbufU[(size_t)((t % 3) * B_ + g * 16 + row) * 256 + dcol];
            const unsigned int* p1 = p0 + 4;
            uint4v ra, rb;
            if (uniform) {
                asm volatile(
                    "global_load_dwordx4 %0, %2, off sc0\n\t"
                    "global_load_dwordx4 %1, %3, off sc0\n\t"
                    "s_waitcnt vmcnt(0)"
                    : "=v"(ra), "=v"(rb) : "v"(p0), "v"(p1) : "memory");
            } else {
                asm volatile(
                    "global_load_dwordx4 %0, %2, off sc0 sc1\n\t"
                    "global_load_dwordx4 %1, %3, off sc0 sc1\n\t"
                    "s_waitcnt vmcnt(0)"
                    : "=v"(ra), "=v"(rb) : "v"(p0), "v"(p1) : "memory");
            }
            *(uint4v*)&hS[row * 520 + dcol * 2]     = ra;
            *(uint4v*)&hS[row * 520 + dcol * 2 + 8] = rb;
        }
        // x(t+1) register prefetch: after poll so its HBM wait never gates it
        if (t + 1 < S_) {
            const float* xsrc = &X[((size_t)(g * 16 + urow) * S_ + (t + 1)) * D_ + upair * 8];
            xr0 = *(const float4*)xsrc;
            xr1 = *(const float4*)(xsrc + 4);
        }
        lds_barrier();   // D: hS visible

        // ---- E: recurrent GEMM + combine + activations ----
        f32x4 accB0 = {0.f, 0.f, 0.f, 0.f};
        f32x4 accB1 = {0.f, 0.f, 0.f, 0.f};
        #pragma unroll
        for (int ks = 0; ks < 16; ++ks) {
            bf16x8 a = *(const bf16x8*)&hS[m * 520 + ks * 32 + q * 8];
            accB0 = __builtin_amdgcn_mfma_f32_16x16x32_bf16(a, UF[0][ks], accB0, 0, 0, 0);
            accB1 = __builtin_amdgcn_mfma_f32_16x16x32_bf16(a, UF[1][ks], accB1, 0, 0, 0);
        }
        #pragma unroll
        for (int j = 0; j < 4; ++j) {
            float v0 = accA0[j] + accB0[j];
            float v1 = accA1[j] + accB1[j];
            v0 = (gate < 3) ? sigmoid_f(v0) : tanh_f(v0);
            v1 = (gate < 3) ? sigmoid_f(v1) : tanh_f(v1);
            gact[gate][q * 4 + j][half * 32 + m]      = v0;
            gact[gate][q * 4 + j][half * 32 + 16 + m] = v1;
        }
        lds_barrier();   // F: gact visible

        // ---- G: update, h store, xS write, drain, flag release ----
        float2 f2v = *(const float2*)&gact[0][urow][2 * upair];
        float2 i2v = *(const float2*)&gact[1][urow][2 * upair];
        float2 o2v = *(const float2*)&gact[2][urow][2 * upair];
        float2 ch2 = *(const float2*)&gact[3][urow][2 * upair];
        cr0 = f2v.x * cr0 + i2v.x * ch2.x;
        cr1 = f2v.y * cr1 + i2v.y * ch2.y;
        float hv0 = o2v.x * tanh_f(cr0);
        float hv1 = o2v.y * tanh_f(cr1);

        float pv = hv0 * wfc2.x + hv1 * wfc2.y;

        if (t < S_ - 1) {
            unsigned int packed = (unsigned int)f2bf(hv0) | ((unsigned int)f2bf(hv1) << 16);
            unsigned int* hdst =
                &hbufU[(size_t)(((t + 1) % 3) * B_ + g * 16 + urow) * 256 + s * 32 + upair];
            if (uniform) {
                asm volatile("global_store_dword %0, %1, off sc0" :: "v"(hdst), "v"(packed) : "memory");
            } else {
                asm volatile("global_store_dword %0, %1, off sc0 sc1" :: "v"(hdst), "v"(packed) : "memory");
            }
            // xS(t+1): f2bf VALU work + xr wait overlap the h-store ack
            bf16x8 v;
            v[0] = (short)f2bf(xr0.x); v[1] = (short)f2bf(xr0.y);
            v[2] = (short)f2bf(xr0.z); v[3] = (short)f2bf(xr0.w);
            v[4] = (short)f2bf(xr1.x); v[5] = (short)f2bf(xr1.y);
            v[6] = (short)f2bf(xr1.z); v[7] = (short)f2bf(xr1.w);
            *(bf16x8*)&xS[urow * 264 + upair * 8] = v;

            asm volatile("s_waitcnt vmcnt(0)" ::: "memory");   // h-stores acked in L2
            if (lane == 0) {
                unsigned int tv = (unsigned int)(t + 1);
                unsigned int* fpA = &flagsG[myflag * 32];
                unsigned int* fpB = fpA + 16;
                if (uniform) {
                    // word A: L2 RMW (coherent with the RMW poll by construction)
                    asm volatile("global_atomic_swap %0, %1, off"
                                 :: "v"(fpA), "v"(tv) : "memory");
                    // word B: write-through for the L3 fallback observers
                    asm volatile("global_store_dword %0, %1, off sc0 sc1"
                                 :: "v"(fpB), "v"(tv) : "memory");
                } else {
                    __hip_atomic_store(fpB, tv, __ATOMIC_RELAXED, __HIP_MEMORY_SCOPE_AGENT);
                }
            }
        } else {
            *(float2*)&outH[(g * 16 + urow) * H_ + s * 64 + 2 * upair] = make_float2(hv0, hv1);
            *(float2*)&outC[(g * 16 + urow) * H_ + s * 64 + 2 * upair] = make_float2(cr0, cr1);
        }

        // ---- pred head (off the inter-block critical path; R0-proven) ----
        pv += __shfl_xor(pv, 16);
        pv += __shfl_xor(pv, 8);
        pv += __shfl_xor(pv, 4);
        pv += __shfl_xor(pv, 2);
        pv += __shfl_xor(pv, 1);
        if (upair == 0) atomicAdd(&pred[(g * 16 + urow) * S_ + t], pv);
    }
}

__global__ void pred_fin(const float* __restrict__ pred,
                         const float* __restrict__ bfc,
                         float* __restrict__ out)
{
    int i = blockIdx.x * blockDim.x + threadIdx.x;
    if (i < B_ * S_) out[i] = pred[i] + bfc[0];
}

extern "C" void kernel_launch(void* const* d_in, const int* in_sizes, int n_in,
                              void* d_out, int out_size, void* d_ws, size_t ws_size,
                              hipStream_t stream) {
    const float* X   = (const float*)d_in[0];
    const float* Wf  = (const float*)d_in[1];
    const float* Wi  = (const float*)d_in[2];
    const float* Wo  = (const float*)d_in[3];
    const float* Wc  = (const float*)d_in[4];
    const float* bfp = (const float*)d_in[5];
    const float* bip = (const float*)d_in[6];
    const float* bop = (const float*)d_in[7];
    const float* bcp = (const float*)d_in[8];
    const float* Uf  = (const float*)d_in[9];
    const float* Ui  = (const float*)d_in[10];
    const float* Uo  = (const float*)d_in[11];
    const float* Uc  = (const float*)d_in[12];
    const float* Wfc = (const float*)d_in[13];
    const float* bfc = (const float*)d_in[14];

    // ws layout:
    //   pred fp32 [64][512]        @0       (131072 B)
    //   hbuf u32 [3][64][256]      @131072  (196608 B)
    //   flags [4 grp][64][32 u32]  @327680  (32768 B; word A @+0, word B @+64B)
    //   xcdtab                     @360448  (256 B)
    float*        pred   = (float*)d_ws;
    unsigned int* hbufU  = (unsigned int*)((char*)d_ws + 131072);
    unsigned int* flags  = (unsigned int*)((char*)d_ws + 327680);
    unsigned int* xcdtab = (unsigned int*)((char*)d_ws + 360448);

    hipMemsetAsync(d_ws, 0, 360704, stream);   // pred, hbuf, flags, xcdtab

    float* out = (float*)d_out;
    lstm_rec<<<64, 512, 0, stream>>>(X, Wf, Wi, Wo, Wc, bfp, bip, bop, bcp,
                                     Uf, Ui, Uo, Uc, Wfc,
                                     pred, hbufU, flags, xcdtab,
                                     out + 32768, out + 65536);
    pred_fin<<<128, 256, 0, stream>>>(pred, bfc, out);
}

// Round 6
// 2286.055 us; speedup vs baseline: 1.2831x; 1.2831x over previous
//
#include <hip/hip_runtime.h>
#include <hip/hip_bf16.h>

#define B_ 64
#define S_ 512
#define D_ 256
#define H_ 512

typedef __attribute__((ext_vector_type(8))) short bf16x8;
typedef __attribute__((ext_vector_type(4))) float f32x4;
typedef __attribute__((ext_vector_type(4))) unsigned int uint4v;
typedef unsigned short ushort_t;
typedef unsigned long long u64_t;

__device__ __forceinline__ ushort_t f2bf(float f) {
    __hip_bfloat16 h = __float2bfloat16(f);   // RNE rounding
    return *reinterpret_cast<ushort_t*>(&h);
}
__device__ __forceinline__ float sigmoid_f(float x) { return 1.f / (1.f + __expf(-x)); }
__device__ __forceinline__ float tanh_f(float x) { return 1.f - 2.f / (__expf(2.f * x) + 1.f); }

__device__ __forceinline__ void lds_barrier() {
    asm volatile("s_waitcnt lgkmcnt(0)\n\ts_barrier" ::: "memory");
}

// R15 = R12 (best measured, 2190us) + pred-RMW removal.
//  * R14 post-mortem: wave0-only polling + extra barriers serialized
//    detect->wakeup->h-load (R0/R12 overlap these per-wave) -> 2994us.
//    Reverted to R12's all-wave tag-fused protocol wholesale.
//  * R15 change: the per-step pred atomicAdd was an L3 RMW issued right
//    after the h-entry store; the NEXT step's probe vmcnt(0) (in-order
//    retirement) transitively waited its ~700-900cy ack -> ~400-600cy on
//    the critical path EVERY step, in every variant measured so far.
//    Now: pred partials accumulate in LDS (predS[16][512], 32KB; written
//    by 2 lanes/wave -> 2-way bank alias = free), flushed ONCE after the
//    t-loop via atomicAdd (off the recurrence). In-loop vmcnt stream
//    carries only h-entry stores + probe/x loads.
//  * Escalate loop: first 2 rounds sleep-free (snappier near-miss detect);
//    s_sleep(1) backoff from round 3 (storm-safe).
//  * Everything else R12-verbatim: entry = u64 {tag|2xbf16} single store
//    (sc0 sc1 write-through, fire-and-forget, drain-free); probe = sc0
//    dwordx4 + tag check; miss -> agent-atomic u64 loads (L3-fresh, data+
//    tag travel together; no L1-stale-spin possible); 2-slot hbuf; R9 XCD
//    self-ranking; x-prefetch after poll.
__global__ __launch_bounds__(512) void lstm_rec(
    const float* __restrict__ X,
    const float* __restrict__ Wf, const float* __restrict__ Wi,
    const float* __restrict__ Wo, const float* __restrict__ Wc,
    const float* __restrict__ bfp, const float* __restrict__ bip,
    const float* __restrict__ bop, const float* __restrict__ bcp,
    const float* __restrict__ Uf, const float* __restrict__ Ui,
    const float* __restrict__ Uo, const float* __restrict__ Uc,
    const float* __restrict__ Wfc,
    float* __restrict__ pred, u64_t* __restrict__ hbuf,
    unsigned int* __restrict__ xcdtab,
    float* __restrict__ outH, float* __restrict__ outC)
{
    __shared__ ushort_t hS[16 * 520];
    __shared__ ushort_t xS[16 * 264];
    __shared__ float gact[4][16][68];
    __shared__ float predS[16][512];
    __shared__ int meta[2];   // [0]=rank, [1]=uniform

    const int tid  = threadIdx.x;
    const int w    = tid >> 6;
    const int lane = tid & 63;
    const int q    = lane >> 4;
    const int m    = lane & 15;
    const int gate = w >> 1;
    const int half = w & 1;

    // ---- XCD self-assignment: wave 0 computes, LDS-broadcasts (R9-proven) ----
    if (w == 0) {
        unsigned int xcd;
        asm volatile("s_getreg_b32 %0, hwreg(HW_REG_XCC_ID)" : "=s"(xcd));
        xcd &= 15u;
        if (lane == 0)
            __hip_atomic_store(&xcdtab[blockIdx.x], xcd + 1u,
                               __ATOMIC_RELEASE, __HIP_MEMORY_SCOPE_AGENT);
        unsigned int entry;
        for (;;) {
            entry = __hip_atomic_load(&xcdtab[lane], __ATOMIC_ACQUIRE, __HIP_MEMORY_SCOPE_AGENT);
            if (__ballot(entry != 0u) == ~0ull) break;
            __builtin_amdgcn_s_sleep(1);
        }
        const unsigned int xcd_j = entry - 1u;
        const unsigned int key_j = (xcd_j << 8) | (unsigned int)lane;
        const unsigned int mykey = (xcd << 8) | (unsigned int)blockIdx.x;
        const int rank = __popcll(__ballot(key_j < mykey));
        const int c_lt = __popcll(__ballot(xcd_j < xcd));
        const int c_eq = __popcll(__ballot(xcd_j == xcd));
        const int gg   = rank >> 3;
        const bool uni = (c_lt <= gg * 8) && (gg * 8 + 8 <= c_lt + c_eq);
        if (lane == 0) { meta[0] = rank; meta[1] = uni ? 1 : 0; }
    }
    __syncthreads();
    const int  rank    = meta[0];
    const bool uniform = meta[1] != 0;
    if (rank >= 32) return;
    const int g = rank >> 3;
    const int s = rank & 7;

    const int ncol0 = s * 64 + half * 32 + m;
    const int ncol1 = ncol0 + 16;

    const float* Ug = (gate == 0) ? Uf : (gate == 1) ? Ui : (gate == 2) ? Uo : Uc;
    const float* Wg = (gate == 0) ? Wf : (gate == 1) ? Wi : (gate == 2) ? Wo : Wc;
    const float* bg = (gate == 0) ? bfp : (gate == 1) ? bip : (gate == 2) ? bop : bcp;

    const float bias0 = bg[ncol0];
    const float bias1 = bg[ncol1];

    // ---- one-time: B-fragments into registers (fp32 -> bf16 RNE) ----
    bf16x8 UF[2][16];
    bf16x8 WF[2][8];
    #pragma unroll
    for (int tt = 0; tt < 2; ++tt) {
        const int nc = tt ? ncol1 : ncol0;
        #pragma unroll
        for (int ks = 0; ks < 16; ++ks) {
            bf16x8 v;
            #pragma unroll
            for (int j = 0; j < 8; ++j)
                v[j] = (short)f2bf(Ug[(ks * 32 + q * 8 + j) * H_ + nc]);
            UF[tt][ks] = v;
        }
        #pragma unroll
        for (int ks = 0; ks < 8; ++ks) {
            bf16x8 v;
            #pragma unroll
            for (int j = 0; j < 8; ++j)
                v[j] = (short)f2bf(Wg[(ks * 32 + q * 8 + j) * H_ + nc]);
            WF[tt][ks] = v;
        }
    }

    const int urow  = tid >> 5;
    const int upair = tid & 31;
    const float2 wfc2 = *(const float2*)&Wfc[s * 64 + 2 * upair];

    float cr0 = 0.f, cr1 = 0.f;

    // ---- preamble: zero predS; stage x(0) into LDS ----
    #pragma unroll
    for (int i = 0; i < 16; ++i)
        predS[(tid * 16 + i) >> 9][(tid * 16 + i) & 511] = 0.f;
    {
        const float* xsrc = &X[((size_t)(g * 16 + urow) * S_ + 0) * D_ + upair * 8];
        float4 a = *(const float4*)xsrc;
        float4 b = *(const float4*)(xsrc + 4);
        bf16x8 v;
        v[0] = (short)f2bf(a.x); v[1] = (short)f2bf(a.y);
        v[2] = (short)f2bf(a.z); v[3] = (short)f2bf(a.w);
        v[4] = (short)f2bf(b.x); v[5] = (short)f2bf(b.y);
        v[6] = (short)f2bf(b.z); v[7] = (short)f2bf(b.w);
        *(bf16x8*)&xS[urow * 264 + upair * 8] = v;
    }

    float4 xr0, xr1;

    for (int t = 0; t < S_; ++t) {
        // ---- C: fused poll+load of h(t); entry={tag|2xbf16}, slot t&1.
        //      t=0 hits the memset: tag 0 == t, data 0 == h(0). ----
        {
            const int row = tid >> 5;
            const int pr  = (tid & 31) * 8;    // 8 consecutive u64 entries (64B)
            u64_t* pe = hbuf + ((size_t)((t & 1) * B_ + g * 16 + row) * 256 + pr);
            const unsigned int tg = (unsigned int)t;
            uint4v ra, rb;                     // lo dwords (2xbf16 each)
            bool got = false;
            if (uniform) {
                // fast probe: sc0 (L1-allowed, L2-coherent within XCD)
                uint4v r0, r1, r2, r3;
                asm volatile(
                    "global_load_dwordx4 %0, %4, off sc0\n\t"
                    "global_load_dwordx4 %1, %5, off sc0\n\t"
                    "global_load_dwordx4 %2, %6, off sc0\n\t"
                    "global_load_dwordx4 %3, %7, off sc0\n\t"
                    "s_waitcnt vmcnt(0)"
                    : "=v"(r0), "=v"(r1), "=v"(r2), "=v"(r3)
                    : "v"(pe), "v"(pe + 2), "v"(pe + 4), "v"(pe + 6)
                    : "memory");
                bool ok = r0[1] == tg && r0[3] == tg && r1[1] == tg && r1[3] == tg
                       && r2[1] == tg && r2[3] == tg && r3[1] == tg && r3[3] == tg;
                if (__ballot(ok) == ~0ull) {
                    ra[0] = r0[0]; ra[1] = r0[2]; ra[2] = r1[0]; ra[3] = r1[2];
                    rb[0] = r2[0]; rb[1] = r2[2]; rb[2] = r3[0]; rb[3] = r3[2];
                    got = true;
                }
            }
            if (!got) {
                // escalation: agent-atomic u64 loads (L2-bypass, L3-fresh).
                // Data+tag travel together, so whichever round sees tag==t
                // carries h(t). First 2 rounds sleep-free (near-miss case);
                // s_sleep backoff from round 3 (storm-safe).
                int rounds = 0;
                for (;;) {
                    u64_t e0 = __hip_atomic_load(pe + 0, __ATOMIC_RELAXED, __HIP_MEMORY_SCOPE_AGENT);
                    u64_t e1 = __hip_atomic_load(pe + 1, __ATOMIC_RELAXED, __HIP_MEMORY_SCOPE_AGENT);
                    u64_t e2 = __hip_atomic_load(pe + 2, __ATOMIC_RELAXED, __HIP_MEMORY_SCOPE_AGENT);
                    u64_t e3 = __hip_atomic_load(pe + 3, __ATOMIC_RELAXED, __HIP_MEMORY_SCOPE_AGENT);
                    u64_t e4 = __hip_atomic_load(pe + 4, __ATOMIC_RELAXED, __HIP_MEMORY_SCOPE_AGENT);
                    u64_t e5 = __hip_atomic_load(pe + 5, __ATOMIC_RELAXED, __HIP_MEMORY_SCOPE_AGENT);
                    u64_t e6 = __hip_atomic_load(pe + 6, __ATOMIC_RELAXED, __HIP_MEMORY_SCOPE_AGENT);
                    u64_t e7 = __hip_atomic_load(pe + 7, __ATOMIC_RELAXED, __HIP_MEMORY_SCOPE_AGENT);
                    bool ok = (unsigned int)(e0 >> 32) == tg && (unsigned int)(e1 >> 32) == tg
                           && (unsigned int)(e2 >> 32) == tg && (unsigned int)(e3 >> 32) == tg
                           && (unsigned int)(e4 >> 32) == tg && (unsigned int)(e5 >> 32) == tg
                           && (unsigned int)(e6 >> 32) == tg && (unsigned int)(e7 >> 32) == tg;
                    if (__ballot(ok) == ~0ull) {
                        ra[0] = (unsigned int)e0; ra[1] = (unsigned int)e1;
                        ra[2] = (unsigned int)e2; ra[3] = (unsigned int)e3;
                        rb[0] = (unsigned int)e4; rb[1] = (unsigned int)e5;
                        rb[2] = (unsigned int)e6; rb[3] = (unsigned int)e7;
                        break;
                    }
                    if (++rounds > 2) __builtin_amdgcn_s_sleep(1);
                }
            }
            // x(t+1) register prefetch: issued after the poll resolves so the
            // poll waitcnts never wait on HBM; consumed in G (~1 phase later)
            if (t + 1 < S_) {
                const float* xsrc = &X[((size_t)(g * 16 + urow) * S_ + (t + 1)) * D_ + upair * 8];
                xr0 = *(const float4*)xsrc;
                xr1 = *(const float4*)(xsrc + 4);
            }
            *(uint4v*)&hS[row * 520 + pr * 2]     = ra;
            *(uint4v*)&hS[row * 520 + pr * 2 + 8] = rb;
        }
        lds_barrier();   // D

        // ---- E: gate GEMMs + activations ----
        f32x4 accA0 = {bias0, bias0, bias0, bias0};
        f32x4 accA1 = {bias1, bias1, bias1, bias1};
        f32x4 accB0 = {0.f, 0.f, 0.f, 0.f};
        f32x4 accB1 = {0.f, 0.f, 0.f, 0.f};
        #pragma unroll
        for (int ks = 0; ks < 8; ++ks) {
            bf16x8 a = *(const bf16x8*)&xS[m * 264 + ks * 32 + q * 8];
            accA0 = __builtin_amdgcn_mfma_f32_16x16x32_bf16(a, WF[0][ks], accA0, 0, 0, 0);
            accA1 = __builtin_amdgcn_mfma_f32_16x16x32_bf16(a, WF[1][ks], accA1, 0, 0, 0);
        }
        #pragma unroll
        for (int ks = 0; ks < 16; ++ks) {
            bf16x8 a = *(const bf16x8*)&hS[m * 520 + ks * 32 + q * 8];
            accB0 = __builtin_amdgcn_mfma_f32_16x16x32_bf16(a, UF[0][ks], accB0, 0, 0, 0);
            accB1 = __builtin_amdgcn_mfma_f32_16x16x32_bf16(a, UF[1][ks], accB1, 0, 0, 0);
        }
        #pragma unroll
        for (int j = 0; j < 4; ++j) {
            float v0 = accA0[j] + accB0[j];
            float v1 = accA1[j] + accB1[j];
            v0 = (gate < 3) ? sigmoid_f(v0) : tanh_f(v0);
            v1 = (gate < 3) ? sigmoid_f(v1) : tanh_f(v1);
            gact[gate][q * 4 + j][half * 32 + m]      = v0;
            gact[gate][q * 4 + j][half * 32 + 16 + m] = v1;
        }
        lds_barrier();   // F

        // ---- G: update; ONE write-through {tag|data} store, fire-and-forget ----
        float2 f2v = *(const float2*)&gact[0][urow][2 * upair];
        float2 i2v = *(const float2*)&gact[1][urow][2 * upair];
        float2 o2v = *(const float2*)&gact[2][urow][2 * upair];
        float2 ch2 = *(const float2*)&gact[3][urow][2 * upair];
        cr0 = f2v.x * cr0 + i2v.x * ch2.x;
        cr1 = f2v.y * cr1 + i2v.y * ch2.y;
        float hv0 = o2v.x * tanh_f(cr0);
        float hv1 = o2v.y * tanh_f(cr1);

        if (t < S_ - 1) {
            unsigned int packed = (unsigned int)f2bf(hv0) | ((unsigned int)f2bf(hv1) << 16);
            u64_t ent = ((u64_t)(unsigned int)(t + 1) << 32) | (u64_t)packed;
            u64_t* hdst = hbuf + ((size_t)(((t + 1) & 1) * B_ + g * 16 + urow) * 256
                                  + s * 32 + upair);
            // sc0 sc1 write-through: local-L2 update + L3 forward. No drain.
            asm volatile("global_store_dwordx2 %0, %1, off sc0 sc1"
                         :: "v"(hdst), "v"(ent) : "memory");
            // xS(t+1): the f2bf VALU work + xr wait overlap the in-flight store
            bf16x8 v;
            v[0] = (short)f2bf(xr0.x); v[1] = (short)f2bf(xr0.y);
            v[2] = (short)f2bf(xr0.z); v[3] = (short)f2bf(xr0.w);
            v[4] = (short)f2bf(xr1.x); v[5] = (short)f2bf(xr1.y);
            v[6] = (short)f2bf(xr1.z); v[7] = (short)f2bf(xr1.w);
            *(bf16x8*)&xS[urow * 264 + upair * 8] = v;
        } else {
            *(float2*)&outH[(g * 16 + urow) * H_ + s * 64 + 2 * upair] = make_float2(hv0, hv1);
            *(float2*)&outC[(g * 16 + urow) * H_ + s * 64 + 2 * upair] = make_float2(cr0, cr1);
        }

        // ---- pred head: reduce to LDS (NO global RMW in the loop) ----
        float pv = hv0 * wfc2.x + hv1 * wfc2.y;
        pv += __shfl_xor(pv, 16);
        pv += __shfl_xor(pv, 8);
        pv += __shfl_xor(pv, 4);
        pv += __shfl_xor(pv, 2);
        pv += __shfl_xor(pv, 1);
        if (upair == 0) predS[urow][t] = pv;   // 2 lanes/wave, 2-way bank = free
    }

    // ---- one-time pred flush: cross-slice sum via atomicAdd (off recurrence) ----
    lds_barrier();
    #pragma unroll
    for (int i = 0; i < 16; ++i) {
        const int idx = tid * 16 + i;
        const int row = idx >> 9;
        const int tt  = idx & 511;
        atomicAdd(&pred[(g * 16 + row) * S_ + tt], predS[row][tt]);
    }
}

__global__ void pred_fin(const float* __restrict__ pred,
                         const float* __restrict__ bfc,
                         float* __restrict__ out)
{
    int i = blockIdx.x * blockDim.x + threadIdx.x;
    if (i < B_ * S_) out[i] = pred[i] + bfc[0];
}

extern "C" void kernel_launch(void* const* d_in, const int* in_sizes, int n_in,
                              void* d_out, int out_size, void* d_ws, size_t ws_size,
                              hipStream_t stream) {
    const float* X   = (const float*)d_in[0];
    const float* Wf  = (const float*)d_in[1];
    const float* Wi  = (const float*)d_in[2];
    const float* Wo  = (const float*)d_in[3];
    const float* Wc  = (const float*)d_in[4];
    const float* bfp = (const float*)d_in[5];
    const float* bip = (const float*)d_in[6];
    const float* bop = (const float*)d_in[7];
    const float* bcp = (const float*)d_in[8];
    const float* Uf  = (const float*)d_in[9];
    const float* Ui  = (const float*)d_in[10];
    const float* Uo  = (const float*)d_in[11];
    const float* Uc  = (const float*)d_in[12];
    const float* Wfc = (const float*)d_in[13];
    const float* bfc = (const float*)d_in[14];

    // ws layout: pred fp32 [64][512] @0 (131072 B)
    //            | hbuf u64 [2][64][256] @131072 (262144 B)
    //            | xcdtab @393216 (256 B)
    float*        pred   = (float*)d_ws;
    u64_t*        hbuf   = (u64_t*)((char*)d_ws + 131072);
    unsigned int* xcdtab = (unsigned int*)((char*)d_ws + 393216);

    hipMemsetAsync(d_ws, 0, 393216 + 256, stream);   // pred, hbuf (tags=0), xcdtab

    float* out = (float*)d_out;
    lstm_rec<<<64, 512, 0, stream>>>(X, Wf, Wi, Wo, Wc, bfp, bip, bop, bcp,
                                     Uf, Ui, Uo, Uc, Wfc,
                                     pred, hbuf, xcdtab,
                                     out + 32768, out + 65536);
    pred_fin<<<128, 256, 0, stream>>>(pred, bfc, out);
}

// Round 8
// 2180.797 us; speedup vs baseline: 1.3451x; 1.0483x over previous
//
#include <hip/hip_runtime.h>
#include <hip/hip_bf16.h>

#define B_ 64
#define S_ 512
#define D_ 256
#define H_ 512

typedef __attribute__((ext_vector_type(8))) short bf16x8;
typedef __attribute__((ext_vector_type(4))) float f32x4;
typedef __attribute__((ext_vector_type(4))) unsigned int uint4v;
typedef unsigned short ushort_t;
typedef unsigned long long u64_t;

__device__ __forceinline__ ushort_t f2bf(float f) {
    __hip_bfloat16 h = __float2bfloat16(f);   // RNE rounding
    return *reinterpret_cast<ushort_t*>(&h);
}
__device__ __forceinline__ float sigmoid_f(float x) { return 1.f / (1.f + __expf(-x)); }
__device__ __forceinline__ float tanh_f(float x) { return 1.f - 2.f / (__expf(2.f * x) + 1.f); }

__device__ __forceinline__ void lds_barrier() {
    asm volatile("s_waitcnt lgkmcnt(0)\n\ts_barrier" ::: "memory");
}

// R17: DVFS probe, hardened resubmit (R16 died on container failure, never ran).
//  * Motivation: per-step wall (~4.4us) invariant across 4 protocols (R0/R12/
//    R14/R15 = 2.2-3.0ms) at ~4.5% pipe utilization. Either the serial chain
//    runs at a DOWNCLOCKED rate (SMU sees 3% util -> ~1GHz; every latency
//    segment inflated ~2x) or it's latency-bound at full clock. This probe
//    separates the two.
//  * Hardening vs R16: grid 256 (64 worker + 192 ballast, <=1 block/CU, no
//    worker-CU sharing); ballast = SINGLE dependent FMA chain (~50% VALU on
//    ballast CUs, ~59TF chip-wide, far under power envelope); done-poll by
//    lane 0 only + __shfl broadcast (no atomic-load storm); safety cap 1<<16
//    outers (~28ms) -> unconditionally hang-proof.
//  * Worker = R12 VERBATIM (best measured, 2230us).
//  * Readout: faster -> downclock confirmed; slower -> power-capped;
//    neutral -> clock theory dead, restructure chain next.
__global__ __launch_bounds__(512) void lstm_rec(
    const float* __restrict__ X,
    const float* __restrict__ Wf, const float* __restrict__ Wi,
    const float* __restrict__ Wo, const float* __restrict__ Wc,
    const float* __restrict__ bfp, const float* __restrict__ bip,
    const float* __restrict__ bop, const float* __restrict__ bcp,
    const float* __restrict__ Uf, const float* __restrict__ Ui,
    const float* __restrict__ Uo, const float* __restrict__ Uc,
    const float* __restrict__ Wfc,
    float* __restrict__ pred, u64_t* __restrict__ hbuf,
    unsigned int* __restrict__ xcdtab, unsigned int* __restrict__ done,
    float* __restrict__ outH, float* __restrict__ outC)
{
    __shared__ ushort_t hS[16 * 520];
    __shared__ ushort_t xS[16 * 264];
    __shared__ float gact[4][16][68];
    __shared__ int meta[2];   // [0]=rank, [1]=uniform

    // ================= ballast path (blocks 64..255) =================
    if (blockIdx.x >= 64) {
        const int lane = threadIdx.x & 63;
        float r0 = 1.0f + (float)(threadIdx.x & 7) * 0.125f;
        const float c = 0.999999f, d = 1e-6f;
        int outer = 0;
        for (;;) {
            #pragma unroll
            for (int i = 0; i < 256; ++i)
                r0 = __builtin_fmaf(r0, c, d);
            ++outer;
            unsigned int dv = 0;
            if (lane == 0)
                dv = __hip_atomic_load(done, __ATOMIC_RELAXED, __HIP_MEMORY_SCOPE_AGENT);
            dv = __shfl(dv, 0);
            if (dv >= 32u || outer > (1 << 16)) break;   // cap ~28ms: hang-proof
        }
        if (r0 == 3.141592f && threadIdx.x == 0)
            done[8] = 1u;   // unreachable; defeats DCE of the spin
        return;
    }

    // ================= worker path: R12 verbatim =====================
    const int tid  = threadIdx.x;
    const int w    = tid >> 6;
    const int lane = tid & 63;
    const int q    = lane >> 4;
    const int m    = lane & 15;
    const int gate = w >> 1;
    const int half = w & 1;

    // ---- XCD self-assignment: wave 0 computes, LDS-broadcasts (R9-proven) ----
    if (w == 0) {
        unsigned int xcd;
        asm volatile("s_getreg_b32 %0, hwreg(HW_REG_XCC_ID)" : "=s"(xcd));
        xcd &= 15u;
        if (lane == 0)
            __hip_atomic_store(&xcdtab[blockIdx.x], xcd + 1u,
                               __ATOMIC_RELEASE, __HIP_MEMORY_SCOPE_AGENT);
        unsigned int entry;
        for (;;) {
            entry = __hip_atomic_load(&xcdtab[lane], __ATOMIC_ACQUIRE, __HIP_MEMORY_SCOPE_AGENT);
            if (__ballot(entry != 0u) == ~0ull) break;
            __builtin_amdgcn_s_sleep(1);
        }
        const unsigned int xcd_j = entry - 1u;
        const unsigned int key_j = (xcd_j << 8) | (unsigned int)lane;
        const unsigned int mykey = (xcd << 8) | (unsigned int)blockIdx.x;
        const int rank = __popcll(__ballot(key_j < mykey));
        const int c_lt = __popcll(__ballot(xcd_j < xcd));
        const int c_eq = __popcll(__ballot(xcd_j == xcd));
        const int gg   = rank >> 3;
        const bool uni = (c_lt <= gg * 8) && (gg * 8 + 8 <= c_lt + c_eq);
        if (lane == 0) { meta[0] = rank; meta[1] = uni ? 1 : 0; }
    }
    __syncthreads();
    const int  rank    = meta[0];
    const bool uniform = meta[1] != 0;
    if (rank >= 32) return;
    const int g = rank >> 3;
    const int s = rank & 7;

    const int ncol0 = s * 64 + half * 32 + m;
    const int ncol1 = ncol0 + 16;

    const float* Ug = (gate == 0) ? Uf : (gate == 1) ? Ui : (gate == 2) ? Uo : Uc;
    const float* Wg = (gate == 0) ? Wf : (gate == 1) ? Wi : (gate == 2) ? Wo : Wc;
    const float* bg = (gate == 0) ? bfp : (gate == 1) ? bip : (gate == 2) ? bop : bcp;

    const float bias0 = bg[ncol0];
    const float bias1 = bg[ncol1];

    // ---- one-time: B-fragments into registers (fp32 -> bf16 RNE) ----
    bf16x8 UF[2][16];
    bf16x8 WF[2][8];
    #pragma unroll
    for (int tt = 0; tt < 2; ++tt) {
        const int nc = tt ? ncol1 : ncol0;
        #pragma unroll
        for (int ks = 0; ks < 16; ++ks) {
            bf16x8 v;
            #pragma unroll
            for (int j = 0; j < 8; ++j)
                v[j] = (short)f2bf(Ug[(ks * 32 + q * 8 + j) * H_ + nc]);
            UF[tt][ks] = v;
        }
        #pragma unroll
        for (int ks = 0; ks < 8; ++ks) {
            bf16x8 v;
            #pragma unroll
            for (int j = 0; j < 8; ++j)
                v[j] = (short)f2bf(Wg[(ks * 32 + q * 8 + j) * H_ + nc]);
            WF[tt][ks] = v;
        }
    }

    const int urow  = tid >> 5;
    const int upair = tid & 31;
    const float2 wfc2 = *(const float2*)&Wfc[s * 64 + 2 * upair];

    float cr0 = 0.f, cr1 = 0.f;

    // ---- preamble: stage x(0) into LDS ----
    {
        const float* xsrc = &X[((size_t)(g * 16 + urow) * S_ + 0) * D_ + upair * 8];
        float4 a = *(const float4*)xsrc;
        float4 b = *(const float4*)(xsrc + 4);
        bf16x8 v;
        v[0] = (short)f2bf(a.x); v[1] = (short)f2bf(a.y);
        v[2] = (short)f2bf(a.z); v[3] = (short)f2bf(a.w);
        v[4] = (short)f2bf(b.x); v[5] = (short)f2bf(b.y);
        v[6] = (short)f2bf(b.z); v[7] = (short)f2bf(b.w);
        *(bf16x8*)&xS[urow * 264 + upair * 8] = v;
    }

    float4 xr0, xr1;

    for (int t = 0; t < S_; ++t) {
        // ---- C: fused poll+load of h(t); entry={tag|2xbf16}, slot t&1.
        //      t=0 hits the memset: tag 0 == t, data 0 == h(0). ----
        {
            const int row = tid >> 5;
            const int pr  = (tid & 31) * 8;    // 8 consecutive u64 entries (64B)
            u64_t* pe = hbuf + ((size_t)((t & 1) * B_ + g * 16 + row) * 256 + pr);
            const unsigned int tg = (unsigned int)t;
            uint4v ra, rb;                     // lo dwords (2xbf16 each)
            bool got = false;
            if (uniform) {
                // fast probe: sc0 (L1-allowed, L2-coherent within XCD)
                uint4v r0, r1, r2, r3;
                asm volatile(
                    "global_load_dwordx4 %0, %4, off sc0\n\t"
                    "global_load_dwordx4 %1, %5, off sc0\n\t"
                    "global_load_dwordx4 %2, %6, off sc0\n\t"
                    "global_load_dwordx4 %3, %7, off sc0\n\t"
                    "s_waitcnt vmcnt(0)"
                    : "=v"(r0), "=v"(r1), "=v"(r2), "=v"(r3)
                    : "v"(pe), "v"(pe + 2), "v"(pe + 4), "v"(pe + 6)
                    : "memory");
                bool ok = r0[1] == tg && r0[3] == tg && r1[1] == tg && r1[3] == tg
                       && r2[1] == tg && r2[3] == tg && r3[1] == tg && r3[3] == tg;
                if (__ballot(ok) == ~0ull) {
                    ra[0] = r0[0]; ra[1] = r0[2]; ra[2] = r1[0]; ra[3] = r1[2];
                    rb[0] = r2[0]; rb[1] = r2[2]; rb[2] = r3[0]; rb[3] = r3[2];
                    got = true;
                }
            }
            if (!got) {
                // escalation: agent-atomic u64 loads (L2-bypass, L3-fresh),
                // s_sleep backoff between rounds. Data+tag travel together,
                // so whichever load sees tag==t carries h(t).
                for (;;) {
                    u64_t e0 = __hip_atomic_load(pe + 0, __ATOMIC_RELAXED, __HIP_MEMORY_SCOPE_AGENT);
                    u64_t e1 = __hip_atomic_load(pe + 1, __ATOMIC_RELAXED, __HIP_MEMORY_SCOPE_AGENT);
                    u64_t e2 = __hip_atomic_load(pe + 2, __ATOMIC_RELAXED, __HIP_MEMORY_SCOPE_AGENT);
                    u64_t e3 = __hip_atomic_load(pe + 3, __ATOMIC_RELAXED, __HIP_MEMORY_SCOPE_AGENT);
                    u64_t e4 = __hip_atomic_load(pe + 4, __ATOMIC_RELAXED, __HIP_MEMORY_SCOPE_AGENT);
                    u64_t e5 = __hip_atomic_load(pe + 5, __ATOMIC_RELAXED, __HIP_MEMORY_SCOPE_AGENT);
                    u64_t e6 = __hip_atomic_load(pe + 6, __ATOMIC_RELAXED, __HIP_MEMORY_SCOPE_AGENT);
                    u64_t e7 = __hip_atomic_load(pe + 7, __ATOMIC_RELAXED, __HIP_MEMORY_SCOPE_AGENT);
                    bool ok = (unsigned int)(e0 >> 32) == tg && (unsigned int)(e1 >> 32) == tg
                           && (unsigned int)(e2 >> 32) == tg && (unsigned int)(e3 >> 32) == tg
                           && (unsigned int)(e4 >> 32) == tg && (unsigned int)(e5 >> 32) == tg
                           && (unsigned int)(e6 >> 32) == tg && (unsigned int)(e7 >> 32) == tg;
                    if (__ballot(ok) == ~0ull) {
                        ra[0] = (unsigned int)e0; ra[1] = (unsigned int)e1;
                        ra[2] = (unsigned int)e2; ra[3] = (unsigned int)e3;
                        rb[0] = (unsigned int)e4; rb[1] = (unsigned int)e5;
                        rb[2] = (unsigned int)e6; rb[3] = (unsigned int)e7;
                        break;
                    }
                    __builtin_amdgcn_s_sleep(1);
                }
            }
            // x(t+1) register prefetch: issued after the poll resolves so the
            // poll waitcnts never wait on HBM; consumed in G (~1 phase later)
            if (t + 1 < S_) {
                const float* xsrc = &X[((size_t)(g * 16 + urow) * S_ + (t + 1)) * D_ + upair * 8];
                xr0 = *(const float4*)xsrc;
                xr1 = *(const float4*)(xsrc + 4);
            }
            *(uint4v*)&hS[row * 520 + pr * 2]     = ra;
            *(uint4v*)&hS[row * 520 + pr * 2 + 8] = rb;
        }
        lds_barrier();   // D

        // ---- E: gate GEMMs + activations ----
        f32x4 accA0 = {bias0, bias0, bias0, bias0};
        f32x4 accA1 = {bias1, bias1, bias1, bias1};
        f32x4 accB0 = {0.f, 0.f, 0.f, 0.f};
        f32x4 accB1 = {0.f, 0.f, 0.f, 0.f};
        #pragma unroll
        for (int ks = 0; ks < 8; ++ks) {
            bf16x8 a = *(const bf16x8*)&xS[m * 264 + ks * 32 + q * 8];
            accA0 = __builtin_amdgcn_mfma_f32_16x16x32_bf16(a, WF[0][ks], accA0, 0, 0, 0);
            accA1 = __builtin_amdgcn_mfma_f32_16x16x32_bf16(a, WF[1][ks], accA1, 0, 0, 0);
        }
        #pragma unroll
        for (int ks = 0; ks < 16; ++ks) {
            bf16x8 a = *(const bf16x8*)&hS[m * 520 + ks * 32 + q * 8];
            accB0 = __builtin_amdgcn_mfma_f32_16x16x32_bf16(a, UF[0][ks], accB0, 0, 0, 0);
            accB1 = __builtin_amdgcn_mfma_f32_16x16x32_bf16(a, UF[1][ks], accB1, 0, 0, 0);
        }
        #pragma unroll
        for (int j = 0; j < 4; ++j) {
            float v0 = accA0[j] + accB0[j];
            float v1 = accA1[j] + accB1[j];
            v0 = (gate < 3) ? sigmoid_f(v0) : tanh_f(v0);
            v1 = (gate < 3) ? sigmoid_f(v1) : tanh_f(v1);
            gact[gate][q * 4 + j][half * 32 + m]      = v0;
            gact[gate][q * 4 + j][half * 32 + 16 + m] = v1;
        }
        lds_barrier();   // F

        // ---- G: update; ONE write-through {tag|data} store, fire-and-forget ----
        float2 f2v = *(const float2*)&gact[0][urow][2 * upair];
        float2 i2v = *(const float2*)&gact[1][urow][2 * upair];
        float2 o2v = *(const float2*)&gact[2][urow][2 * upair];
        float2 ch2 = *(const float2*)&gact[3][urow][2 * upair];
        cr0 = f2v.x * cr0 + i2v.x * ch2.x;
        cr1 = f2v.y * cr1 + i2v.y * ch2.y;
        float hv0 = o2v.x * tanh_f(cr0);
        float hv1 = o2v.y * tanh_f(cr1);

        if (t < S_ - 1) {
            unsigned int packed = (unsigned int)f2bf(hv0) | ((unsigned int)f2bf(hv1) << 16);
            u64_t ent = ((u64_t)(unsigned int)(t + 1) << 32) | (u64_t)packed;
            u64_t* hdst = hbuf + ((size_t)(((t + 1) & 1) * B_ + g * 16 + urow) * 256
                                  + s * 32 + upair);
            // sc0 sc1 write-through: local-L2 update + L3 forward. No drain.
            asm volatile("global_store_dwordx2 %0, %1, off sc0 sc1"
                         :: "v"(hdst), "v"(ent) : "memory");
            // xS(t+1): the f2bf VALU work + xr wait overlap the in-flight store
            bf16x8 v;
            v[0] = (short)f2bf(xr0.x); v[1] = (short)f2bf(xr0.y);
            v[2] = (short)f2bf(xr0.z); v[3] = (short)f2bf(xr0.w);
            v[4] = (short)f2bf(xr1.x); v[5] = (short)f2bf(xr1.y);
            v[6] = (short)f2bf(xr1.z); v[7] = (short)f2bf(xr1.w);
            *(bf16x8*)&xS[urow * 264 + upair * 8] = v;
        } else {
            *(float2*)&outH[(g * 16 + urow) * H_ + s * 64 + 2 * upair] = make_float2(hv0, hv1);
            *(float2*)&outC[(g * 16 + urow) * H_ + s * 64 + 2 * upair] = make_float2(cr0, cr1);
        }

        // ---- pred head (off the inter-block critical path) ----
        float pv = hv0 * wfc2.x + hv1 * wfc2.y;
        pv += __shfl_xor(pv, 16);
        pv += __shfl_xor(pv, 8);
        pv += __shfl_xor(pv, 4);
        pv += __shfl_xor(pv, 2);
        pv += __shfl_xor(pv, 1);
        if (upair == 0) atomicAdd(&pred[(g * 16 + urow) * S_ + t], pv);
    }

    // ---- signal completion to ballast blocks ----
    __syncthreads();
    if (tid == 0)
        __hip_atomic_fetch_add(done, 1u, __ATOMIC_RELEASE, __HIP_MEMORY_SCOPE_AGENT);
}

__global__ void pred_fin(const float* __restrict__ pred,
                         const float* __restrict__ bfc,
                         float* __restrict__ out)
{
    int i = blockIdx.x * blockDim.x + threadIdx.x;
    if (i < B_ * S_) out[i] = pred[i] + bfc[0];
}

extern "C" void kernel_launch(void* const* d_in, const int* in_sizes, int n_in,
                              void* d_out, int out_size, void* d_ws, size_t ws_size,
                              hipStream_t stream) {
    const float* X   = (const float*)d_in[0];
    const float* Wf  = (const float*)d_in[1];
    const float* Wi  = (const float*)d_in[2];
    const float* Wo  = (const float*)d_in[3];
    const float* Wc  = (const float*)d_in[4];
    const float* bfp = (const float*)d_in[5];
    const float* bip = (const float*)d_in[6];
    const float* bop = (const float*)d_in[7];
    const float* bcp = (const float*)d_in[8];
    const float* Uf  = (const float*)d_in[9];
    const float* Ui  = (const float*)d_in[10];
    const float* Uo  = (const float*)d_in[11];
    const float* Uc  = (const float*)d_in[12];
    const float* Wfc = (const float*)d_in[13];
    const float* bfc = (const float*)d_in[14];

    // ws layout: pred fp32 [64][512] @0 (131072 B)
    //            | hbuf u64 [2][64][256] @131072 (262144 B)
    //            | xcdtab @393216 (256 B)
    //            | done @393472 (64 B)
    float*        pred   = (float*)d_ws;
    u64_t*        hbuf   = (u64_t*)((char*)d_ws + 131072);
    unsigned int* xcdtab = (unsigned int*)((char*)d_ws + 393216);
    unsigned int* done   = (unsigned int*)((char*)d_ws + 393472);

    hipMemsetAsync(d_ws, 0, 393536, stream);   // pred, hbuf (tags=0), xcdtab, done

    float* out = (float*)d_out;
    lstm_rec<<<256, 512, 0, stream>>>(X, Wf, Wi, Wo, Wc, bfp, bip, bop, bcp,
                                      Uf, Ui, Uo, Uc, Wfc,
                                      pred, hbuf, xcdtab, done,
                                      out + 32768, out + 65536);
    pred_fin<<<128, 256, 0, stream>>>(pred, bfc, out);
}